// Round 3
// baseline (452.520 us; speedup 1.0000x reference)
//
#include <hip/hip_runtime.h>
#include <math.h>

typedef unsigned long long u64;
typedef unsigned int u32;
typedef unsigned short ushort_t;

// Problem constants
#define TOKENS 1024   // B*S = 2*512
#define DDIM   1024
#define NHEAD  8
#define QD     256
#define HQD    2048   // NHEAD*QD
#define NROWS  8192   // TOKENS*NHEAD
#define NKEY   128
#define TOPK   16

__device__ __forceinline__ ushort_t f2bf(float f) {
    u32 u = __float_as_uint(f);
    u32 r = (u + 0x7FFFu + ((u >> 16) & 1u)) >> 16;   // RNE
    return (ushort_t)r;
}
__device__ __forceinline__ float bf_lo(u32 w) { return __uint_as_float(w << 16); }
__device__ __forceinline__ float bf_hi(u32 w) { return __uint_as_float(w & 0xFFFF0000u); }

// ---------------------------------------------------------------------------
// Fused launch 1 (128 threads/block):
//   blocks [0,1024):     qproj split-K fp32 GEMM, tile 64x64, 8x4/thread
//   blocks [1024,3072):  down/up fp32 -> bf16 conversion (optional)
//   blocks [3072,3328):  sub_key L2-normalize
// ---------------------------------------------------------------------------
__global__ __launch_bounds__(128) void k_fused1(
    const float* __restrict__ A, const float* __restrict__ W,
    float* __restrict__ qp0, float* __restrict__ qp1,
    const float* __restrict__ down, const float* __restrict__ up,
    ushort_t* __restrict__ downb, ushort_t* __restrict__ upb, int doCvt,
    const float* __restrict__ sk0, const float* __restrict__ sk1,
    float* __restrict__ k0n, float* __restrict__ k1n)
{
    __shared__ float smem[2 * 32 * 65];
    const int bid = blockIdx.x;
    const int tid = threadIdx.x;

    if (bid < 1024) {
        // ---------------- qproj split-K ----------------
        float* As = smem;              // [32][65]  ([k][m])
        float* Bs = smem + 32 * 65;    // [32][65]  ([k][n])
        const int par = bid >> 9;            // 0..1  K-half
        const int rem = bid & 511;
        const int bx = rem & 31;             // n-tile
        const int by = rem >> 5;             // m-tile
        const int m0 = by * 64;
        const int n0 = bx * 64;
        float* qp = par ? qp1 : qp0;

        const int aM  = tid & 63;            // staging: row
        const int aKg = tid >> 6;            // 0..1 -> k base 0/16
        const int bK  = tid >> 3;            // 0..15
        const int bN8 = (tid & 7) * 8;       // 0..56
        const int ty  = tid >> 4;            // 0..7 -> m = ty*8
        const int tx  = tid & 15;            // 0..15 -> n = tx*4

        float acc[8][4] = {};
        const int kend = par * 512 + 512;
        for (int kk = par * 512; kk < kend; kk += 32) {
            __syncthreads();
#pragma unroll
            for (int j = 0; j < 4; j++) {
                float4 v = *(const float4*)(A + (size_t)(m0 + aM) * DDIM + kk + aKg * 16 + j * 4);
                const int kb = aKg * 16 + j * 4;
                As[(kb + 0) * 65 + aM] = v.x; As[(kb + 1) * 65 + aM] = v.y;
                As[(kb + 2) * 65 + aM] = v.z; As[(kb + 3) * 65 + aM] = v.w;
            }
#pragma unroll
            for (int p = 0; p < 2; p++) {
                const int k = bK + p * 16;
                float4 v0 = *(const float4*)(W + (size_t)(kk + k) * HQD + n0 + bN8);
                float4 v1 = *(const float4*)(W + (size_t)(kk + k) * HQD + n0 + bN8 + 4);
                *(float4*)&Bs[k * 65 + bN8]     = v0;
                *(float4*)&Bs[k * 65 + bN8 + 4] = v1;
            }
            __syncthreads();
#pragma unroll
            for (int k = 0; k < 32; k++) {
                float a[8], b[4];
                *(float4*)(a)     = *(const float4*)&As[k * 65 + ty * 8];
                *(float4*)(a + 4) = *(const float4*)&As[k * 65 + ty * 8 + 4];
                *(float4*)(b)     = *(const float4*)&Bs[k * 65 + tx * 4];
#pragma unroll
                for (int i = 0; i < 8; i++)
#pragma unroll
                    for (int j = 0; j < 4; j++)
                        acc[i][j] = fmaf(a[i], b[j], acc[i][j]);
            }
        }
#pragma unroll
        for (int i = 0; i < 8; i++) {
            float4 r;
            r.x = acc[i][0]; r.y = acc[i][1]; r.z = acc[i][2]; r.w = acc[i][3];
            *(float4*)(qp + (size_t)(m0 + ty * 8 + i) * HQD + n0 + tx * 4) = r;
        }
    } else if (bid < 3072) {
        // ---------------- fp32 -> bf16 table conversion ----------------
        if (!doCvt) return;
        const int cb = bid - 1024;                 // 0..2047
        const float* src = (cb < 1024) ? down : up;
        ushort_t* dst = (cb < 1024) ? downb : upb;
        const size_t base4 = (size_t)(cb & 1023) * 4096;  // float4 units (16384 elems)
        const float4* s4 = (const float4*)src;
        ushort4* d4 = (ushort4*)dst;
#pragma unroll 4
        for (int it = 0; it < 32; it++) {
            size_t i = base4 + (size_t)it * 128 + tid;
            float4 v = s4[i];
            ushort4 o;
            o.x = f2bf(v.x); o.y = f2bf(v.y); o.z = f2bf(v.z); o.w = f2bf(v.w);
            d4[i] = o;
        }
    } else {
        // ---------------- key L2-normalize ----------------
        const int b = bid - 3072;                  // 0..255
        const float* src = (b < 128) ? sk0 : sk1;
        float* dst = (b < 128) ? k0n : k1n;
        const int row = b & 127;
        float v = src[row * 128 + tid];
        float sq = v * v;
        for (int off = 32; off; off >>= 1) sq += __shfl_down(sq, off);
        if ((tid & 63) == 0) smem[tid >> 6] = sq;
        __syncthreads();
        if (tid == 0) {
            float n = sqrtf(smem[0] + smem[1]);
            smem[2] = 1.0f / fmaxf(n, 1e-12f);
        }
        __syncthreads();
        dst[row * 128 + tid] = v * smem[2];
    }
}

// ---------------------------------------------------------------------------
// K2a: split-K reduce + bias + partial column sums/sumsq; writes q [8192][256]
// ---------------------------------------------------------------------------
__global__ __launch_bounds__(256) void k_bnstat1(const float* __restrict__ qp0,
                                                 const float* __restrict__ qp1,
                                                 const float* __restrict__ bq,
                                                 float* __restrict__ q,
                                                 float* __restrict__ psum,
                                                 float* __restrict__ psq)
{
    const int b = blockIdx.x;   // 0..63
    const int j = threadIdx.x;  // 0..255
    float s = 0.f, sq = 0.f;
    for (int rr = 0; rr < 128; rr++) {
        const int r = b * 128 + rr;
        const size_t g = (size_t)r * 256 + j;
        float v = qp0[g] + qp1[g] + bq[(r & 7) * 256 + j];
        q[g] = v;
        s += v; sq += v * v;
    }
    psum[b * 256 + j] = s;
    psq[b * 256 + j]  = sq;
}

// K2b: finish stats -> mean[j], scale[j] = gamma/sqrt(var+eps)
__global__ __launch_bounds__(256) void k_bnstat2(const float* __restrict__ psum,
                                                 const float* __restrict__ psq,
                                                 const float* __restrict__ gamma,
                                                 float* __restrict__ meanOut,
                                                 float* __restrict__ scaleOut)
{
    const int j = threadIdx.x;
    float s = 0.f, sq = 0.f;
    for (int b = 0; b < 64; b++) {
        s += psum[b * 256 + j];
        sq += psq[b * 256 + j];
    }
    float mean = s * (1.0f / 8192.0f);
    float var = sq * (1.0f / 8192.0f) - mean * mean;
    meanOut[j] = mean;
    scaleOut[j] = gamma[j] / sqrtf(var + 1e-5f);
}

// ---------------------------------------------------------------------------
// K4a: in-place BN transform + per-half L2 normalize of q rows [8192][256]
// ---------------------------------------------------------------------------
__global__ __launch_bounds__(256) void k_bnnorm(float* __restrict__ q,
                                                const float* __restrict__ mean,
                                                const float* __restrict__ scale,
                                                const float* __restrict__ beta)
{
    const int r = blockIdx.x * 4 + (threadIdx.x >> 6);
    const int lane = threadIdx.x & 63;
    const int j = lane * 4;
    float4 v = *(const float4*)(q + (size_t)r * 256 + j);
    float4 m = *(const float4*)(mean + j);
    float4 sc = *(const float4*)(scale + j);
    float4 be = *(const float4*)(beta + j);
    float x0 = (v.x - m.x) * sc.x + be.x;
    float x1 = (v.y - m.y) * sc.y + be.y;
    float x2 = (v.z - m.z) * sc.z + be.z;
    float x3 = (v.w - m.w) * sc.w + be.w;
    float sq = x0 * x0 + x1 * x1 + x2 * x2 + x3 * x3;
    for (int off = 16; off; off >>= 1) sq += __shfl_xor(sq, off);
    float inv = 1.0f / fmaxf(sqrtf(sq), 1e-12f);
    x0 *= inv; x1 *= inv; x2 *= inv; x3 *= inv;
    float4 o; o.x = x0; o.y = x1; o.z = x2; o.w = x3;
    *(float4*)(q + (size_t)r * 256 + j) = o;
}

// ---------------------------------------------------------------------------
// K4b: scores s_half[8192][128] = qn_half [8192][128] @ keys_half^T
// ---------------------------------------------------------------------------
__global__ __launch_bounds__(256) void k_scores(const float* __restrict__ q,
                                                const float* __restrict__ kn0,
                                                const float* __restrict__ kn1,
                                                float* __restrict__ sOut0,
                                                float* __restrict__ sOut1)
{
    __shared__ float Ks[64 * 129];  // [d][n]
    __shared__ float Qs[64 * 65];   // [d][r]
    const int half = blockIdx.y;
    const int row0 = blockIdx.x * 64;
    const float* kn = half ? kn1 : kn0;
    float* sOut = half ? sOut1 : sOut0;
    const int tid = threadIdx.x;
    const int ty = tid >> 5;   // 0..7  -> r = ty*8
    const int tx = tid & 31;   // 0..31 -> n = tx*4
    float acc[8][4] = {};

    for (int c = 0; c < 2; c++) {
        __syncthreads();
        {
            int d4 = (tid & 15) * 4;
            int n = tid >> 4;  // 0..15
#pragma unroll
            for (int p = 0; p < 8; p++) {
                int nn = n + p * 16;
                float4 v = *(const float4*)(kn + nn * 128 + c * 64 + d4);
                Ks[(d4 + 0) * 129 + nn] = v.x; Ks[(d4 + 1) * 129 + nn] = v.y;
                Ks[(d4 + 2) * 129 + nn] = v.z; Ks[(d4 + 3) * 129 + nn] = v.w;
            }
            int r = tid >> 4;
#pragma unroll
            for (int p = 0; p < 4; p++) {
                int rr = r + p * 16;
                float4 v = *(const float4*)(q + (size_t)(row0 + rr) * 256 + half * 128 + c * 64 + d4);
                Qs[(d4 + 0) * 65 + rr] = v.x; Qs[(d4 + 1) * 65 + rr] = v.y;
                Qs[(d4 + 2) * 65 + rr] = v.z; Qs[(d4 + 3) * 65 + rr] = v.w;
            }
        }
        __syncthreads();
#pragma unroll
        for (int d = 0; d < 64; d++) {
            float a[8], b[4];
            *(float4*)(a)     = *(const float4*)&Qs[d * 65 + ty * 8];
            *(float4*)(a + 4) = *(const float4*)&Qs[d * 65 + ty * 8 + 4];
            *(float4*)(b)     = *(const float4*)&Ks[d * 129 + tx * 4];
#pragma unroll
            for (int i = 0; i < 8; i++)
#pragma unroll
                for (int j = 0; j < 4; j++)
                    acc[i][j] = fmaf(a[i], b[j], acc[i][j]);
        }
    }
#pragma unroll
    for (int i = 0; i < 8; i++) {
        float4 r;
        r.x = acc[i][0]; r.y = acc[i][1]; r.z = acc[i][2]; r.w = acc[i][3];
        *(float4*)(sOut + (size_t)(row0 + ty * 8 + i) * 128 + tx * 4) = r;
    }
}

// ---------------------------------------------------------------------------
// K4c: per (token,head) row: exact top-16 + softmax via iterative extraction.
// ---------------------------------------------------------------------------
__device__ __forceinline__ u64 mkkey(float v, u32 idx) {
    u32 ub = __float_as_uint(v);
    ub = (ub & 0x80000000u) ? ~ub : (ub | 0x80000000u);
    return ((u64)ub << 32) | (u64)(0xFFFFFFFFu - idx);
}
__device__ __forceinline__ float keyval(u64 k) {
    u32 ub = (u32)(k >> 32);
    u32 fb = (ub & 0x80000000u) ? (ub ^ 0x80000000u) : ~ub;
    return __uint_as_float(fb);
}
__device__ __forceinline__ u32 keyidx(u64 k) {
    return 0xFFFFFFFFu - (u32)(k & 0xFFFFFFFFu);
}

__global__ __launch_bounds__(256) void k_topk(const float* __restrict__ s0,
                                              const float* __restrict__ s1,
                                              int* __restrict__ tIdx,
                                              float* __restrict__ tW)
{
    __shared__ float shv[4][2][16];
    __shared__ int   shi[4][2][16];
    const int w = threadIdx.x >> 6;
    const int lane = threadIdx.x & 63;
    const int row = blockIdx.x * 4 + w;

#pragma unroll
    for (int h = 0; h < 2; h++) {
        const float* s = h ? s1 : s0;
        float v0 = s[(size_t)row * 128 + lane];
        float v1 = s[(size_t)row * 128 + 64 + lane];
        u64 k0 = mkkey(v0, (u32)lane);
        u64 k1 = mkkey(v1, (u32)(lane + 64));
        for (int r = 0; r < 16; r++) {
            u64 m = (k0 > k1) ? k0 : k1;
#pragma unroll
            for (int off = 1; off < 64; off <<= 1) {
                u64 o = __shfl_xor(m, off);
                if (o > m) m = o;
            }
            if (k0 == m) k0 = 0;
            if (k1 == m) k1 = 0;
            if (lane == 0) { shv[w][h][r] = keyval(m); shi[w][h][r] = (int)keyidx(m); }
        }
    }

    u64 ck[4];
#pragma unroll
    for (int qq = 0; qq < 4; qq++) {
        int id = lane + 64 * qq;
        int a = id >> 4, b = id & 15;
        float v = shv[w][0][a] + shv[w][1][b];
        u32 idx = (u32)(shi[w][0][a] * 128 + shi[w][1][b]);
        ck[qq] = mkkey(v, idx);
    }
    float winv = 0.f; u32 wini = 0;
    for (int r = 0; r < 16; r++) {
        u64 m = ck[0];
#pragma unroll
        for (int qq = 1; qq < 4; qq++) if (ck[qq] > m) m = ck[qq];
#pragma unroll
        for (int off = 1; off < 64; off <<= 1) {
            u64 o = __shfl_xor(m, off);
            if (o > m) m = o;
        }
#pragma unroll
        for (int qq = 0; qq < 4; qq++) if (ck[qq] == m) ck[qq] = 0;
        if (lane == r) { winv = keyval(m); wini = keyidx(m); }
    }
    float vmax = __shfl(winv, 0);
    if (lane < 16) {
        float e = expf(winv - vmax);
        float ssum = e;
#pragma unroll
        for (int off = 1; off < 16; off <<= 1) ssum += __shfl_xor(ssum, off, 16);
        tW[(size_t)row * 16 + lane] = e / ssum;
        tIdx[(size_t)row * 16 + lane] = (int)wini;
    }
}

// ---------------------------------------------------------------------------
// K5a (bf16): coef[t][p] = w[p] * gelu(down[e_p] . hidden[t])
// hidden kept in registers (16 floats/lane); 4-expert preload groups.
// ---------------------------------------------------------------------------
__global__ __launch_bounds__(1024) void k_coef_bf(const float* __restrict__ hidden,
                                                  const ushort_t* __restrict__ downb,
                                                  const int* __restrict__ tIdx,
                                                  const float* __restrict__ tW,
                                                  float* __restrict__ coef)
{
    const int t = blockIdx.x;
    const int wave = threadIdx.x >> 6, lane = threadIdx.x & 63;
    const float* hp = hidden + (size_t)t * 1024;
    float h[16];
    *(float4*)(h + 0)  = *(const float4*)(hp + lane * 8);
    *(float4*)(h + 4)  = *(const float4*)(hp + lane * 8 + 4);
    *(float4*)(h + 8)  = *(const float4*)(hp + 512 + lane * 8);
    *(float4*)(h + 12) = *(const float4*)(hp + 512 + lane * 8 + 4);

#pragma unroll
    for (int g = 0; g < 2; g++) {
        const int pg = wave * 8 + g * 4;
        float s[4];
        uint4 a[4], b[4];
#pragma unroll
        for (int i = 0; i < 4; i++) {
            const int e = tIdx[(size_t)t * 128 + pg + i];
            const uint4* rp = (const uint4*)(downb + (size_t)e * 1024);
            a[i] = rp[lane];
            b[i] = rp[lane + 64];
        }
#pragma unroll
        for (int i = 0; i < 4; i++) {
            float acc = 0.f;
            const u32* aw = (const u32*)&a[i];
            const u32* bw = (const u32*)&b[i];
#pragma unroll
            for (int c = 0; c < 4; c++) {
                acc = fmaf(bf_lo(aw[c]), h[2 * c], acc);
                acc = fmaf(bf_hi(aw[c]), h[2 * c + 1], acc);
                acc = fmaf(bf_lo(bw[c]), h[8 + 2 * c], acc);
                acc = fmaf(bf_hi(bw[c]), h[8 + 2 * c + 1], acc);
            }
            s[i] = acc;
        }
#pragma unroll
        for (int i = 0; i < 4; i++)
#pragma unroll
            for (int off = 1; off < 64; off <<= 1) s[i] += __shfl_xor(s[i], off);
        if (lane < 4) {
            float x = (lane == 0) ? s[0] : (lane == 1) ? s[1] : (lane == 2) ? s[2] : s[3];
            float wv = tW[(size_t)t * 128 + pg + lane];
            float gl = 0.5f * x * (1.0f + erff(x * 0.70710678118654752f));
            coef[(size_t)t * 128 + pg + lane] = wv * gl;
        }
    }
}

// K5a fallback (fp32 tables)
__global__ __launch_bounds__(1024) void k_coef_f32(const float* __restrict__ hidden,
                                                   const float* __restrict__ down,
                                                   const int* __restrict__ tIdx,
                                                   const float* __restrict__ tW,
                                                   float* __restrict__ coef)
{
    __shared__ __align__(16) float hs[1024];
    __shared__ int   eidx[128];
    __shared__ float wv[128];
    const int t = blockIdx.x;
    const int tid = threadIdx.x;
    hs[tid] = hidden[(size_t)t * 1024 + tid];
    if (tid < 128) {
        eidx[tid] = tIdx[(size_t)t * 128 + tid];
        wv[tid]   = tW[(size_t)t * 128 + tid];
    }
    __syncthreads();
    const int wave = tid >> 6, lane = tid & 63;
#pragma unroll 2
    for (int i = 0; i < 8; i++) {
        const int p = wave * 8 + i;
        const float4* dp = (const float4*)(down + (size_t)eidx[p] * 1024);
        float sum = 0.f;
#pragma unroll
        for (int c = 0; c < 4; c++) {
            float4 dv = dp[lane + 64 * c];
            float4 hv = *(const float4*)(hs + (lane + 64 * c) * 4);
            sum += dv.x * hv.x + dv.y * hv.y + dv.z * hv.z + dv.w * hv.w;
        }
        for (int off = 32; off; off >>= 1) sum += __shfl_down(sum, off);
        if (lane == 0) {
            float x = sum;
            float g = 0.5f * x * (1.0f + erff(x * 0.70710678118654752f));
            coef[(size_t)t * 128 + p] = wv[p] * g;
        }
    }
}

// ---------------------------------------------------------------------------
// K5b (bf16): out[t][j] = sum_p coef[t][p] * up[e_p][j]; float4 out/thread
// ---------------------------------------------------------------------------
__global__ __launch_bounds__(256) void k_accum_bf(const ushort_t* __restrict__ upb,
                                                  const int* __restrict__ tIdx,
                                                  const float* __restrict__ coef,
                                                  float* __restrict__ out)
{
    __shared__ float cf[128];
    __shared__ int   ei[128];
    const int t = blockIdx.x;
    const int tid = threadIdx.x;
    if (tid < 128) {
        cf[tid] = coef[(size_t)t * 128 + tid];
        ei[tid] = tIdx[(size_t)t * 128 + tid];
    }
    __syncthreads();
    float4 acc = make_float4(0.f, 0.f, 0.f, 0.f);
#pragma unroll 8
    for (int p = 0; p < 128; p++) {
        const float c = cf[p];
        uint2 v = *(const uint2*)(upb + (size_t)ei[p] * 1024 + tid * 4);
        acc.x = fmaf(c, bf_lo(v.x), acc.x);
        acc.y = fmaf(c, bf_hi(v.x), acc.y);
        acc.z = fmaf(c, bf_lo(v.y), acc.z);
        acc.w = fmaf(c, bf_hi(v.y), acc.w);
    }
    *(float4*)(out + (size_t)t * 1024 + tid * 4) = acc;
}

// K5b fallback (fp32 tables)
__global__ __launch_bounds__(256) void k_accum_f32(const float* __restrict__ up,
                                                   const int* __restrict__ tIdx,
                                                   const float* __restrict__ coef,
                                                   float* __restrict__ out)
{
    __shared__ float cf[128];
    __shared__ int   ei[128];
    const int t = blockIdx.x >> 2;
    const int c = blockIdx.x & 3;
    const int tid = threadIdx.x;
    if (tid < 128) {
        cf[tid] = coef[(size_t)t * 128 + tid];
        ei[tid] = tIdx[(size_t)t * 128 + tid];
    }
    __syncthreads();
    const int j = c * 256 + tid;
    float acc = 0.f;
#pragma unroll 8
    for (int p = 0; p < 128; p++)
        acc = fmaf(cf[p], up[(size_t)ei[p] * 1024 + j], acc);
    out[(size_t)t * 1024 + j] = acc;
}

// ---------------------------------------------------------------------------
extern "C" void kernel_launch(void* const* d_in, const int* in_sizes, int n_in,
                              void* d_out, int out_size, void* d_ws, size_t ws_size,
                              hipStream_t stream)
{
    const float* hidden = (const float*)d_in[0];
    const float* Wq     = (const float*)d_in[1];
    const float* bq     = (const float*)d_in[2];
    const float* gamma  = (const float*)d_in[3];
    const float* beta   = (const float*)d_in[4];
    const float* sk0    = (const float*)d_in[5];
    const float* sk1    = (const float*)d_in[6];
    const float* down   = (const float*)d_in[7];
    const float* up     = (const float*)d_in[8];
    float* out = (float*)d_out;

    float* ws = (float*)d_ws;
    size_t o = 0;
    float* qp0   = ws + o; o += (size_t)TOKENS * HQD;      // 2M
    float* qp1   = ws + o; o += (size_t)TOKENS * HQD;      // 2M
    float* q     = ws + o; o += (size_t)TOKENS * HQD;      // 2M
    float* ps    = ws + o; o += 64 * 256;
    float* pq    = ws + o; o += 64 * 256;
    float* meanb = ws + o; o += 256;
    float* scaleb= ws + o; o += 256;
    float* k0n   = ws + o; o += NKEY * 128;
    float* k1n   = ws + o; o += NKEY * 128;
    float* s0    = ws + o; o += (size_t)NROWS * 128;
    float* s1    = ws + o; o += (size_t)NROWS * 128;
    float* tW    = ws + o; o += (size_t)NROWS * TOPK;
    int*   tIdx  = (int*)(ws + o); o += (size_t)NROWS * TOPK;
    float* coef  = ws + o; o += (size_t)TOKENS * 128;
    // bf16 tables: 16.78M elems each -> 8.39M float slots each
    ushort_t* downb = (ushort_t*)(ws + o); o += (size_t)16384 * 1024 / 2;
    ushort_t* upb   = (ushort_t*)(ws + o); o += (size_t)16384 * 1024 / 2;
    const int useBF = (ws_size >= o * sizeof(float)) ? 1 : 0;

    k_fused1 <<<3328, 128, 0, stream>>>(hidden, Wq, qp0, qp1,
                                        down, up, downb, upb, useBF,
                                        sk0, sk1, k0n, k1n);
    k_bnstat1<<<64, 256, 0, stream>>>(qp0, qp1, bq, q, ps, pq);
    k_bnstat2<<<1, 256, 0, stream>>>(ps, pq, gamma, meanb, scaleb);
    k_bnnorm <<<2048, 256, 0, stream>>>(q, meanb, scaleb, beta);
    k_scores <<<dim3(128, 2), 256, 0, stream>>>(q, k0n, k1n, s0, s1);
    k_topk   <<<2048, 256, 0, stream>>>(s0, s1, tIdx, tW);
    if (useBF) {
        k_coef_bf <<<TOKENS, 1024, 0, stream>>>(hidden, downb, tIdx, tW, coef);
        k_accum_bf<<<TOKENS, 256, 0, stream>>>(upb, tIdx, coef, out);
    } else {
        k_coef_f32 <<<TOKENS, 1024, 0, stream>>>(hidden, down, tIdx, tW, coef);
        k_accum_f32<<<4096, 256, 0, stream>>>(up, tIdx, coef, out);
    }
}

// Round 4
// 244.555 us; speedup vs baseline: 1.8504x; 1.8504x over previous
//
#include <hip/hip_runtime.h>
#include <math.h>

typedef unsigned long long u64;
typedef unsigned int u32;
typedef unsigned short ushort_t;

// Problem constants
#define TOKENS 1024   // B*S = 2*512
#define DDIM   1024
#define NHEAD  8
#define QD     256
#define HQD    2048   // NHEAD*QD
#define NROWS  8192   // TOKENS*NHEAD
#define NKEY   128
#define TOPK   16

__device__ __forceinline__ ushort_t f2bf(float f) {
    u32 u = __float_as_uint(f);
    u32 r = (u + 0x7FFFu + ((u >> 16) & 1u)) >> 16;   // RNE
    return (ushort_t)r;
}
__device__ __forceinline__ float bf_lo(u32 w) { return __uint_as_float(w << 16); }
__device__ __forceinline__ float bf_hi(u32 w) { return __uint_as_float(w & 0xFFFF0000u); }

// ---------------------------------------------------------------------------
// Fused launch 1 (256 threads/block):
//   blocks [0,1024):     qproj split-K(2) fp32 GEMM, tile 64x64, 4x4/thread
//                        (round-2 verified body: even pad 68, aligned b128)
//   blocks [1024,3072):  down/up fp32 -> bf16 conversion (overlaps qproj)
//   blocks [3072,3200):  sub_key L2-normalize (2 rows/block)
// ---------------------------------------------------------------------------
__global__ __launch_bounds__(256) void k_fused1(
    const float* __restrict__ A, const float* __restrict__ W,
    float* __restrict__ qp0, float* __restrict__ qp1,
    const float* __restrict__ down, const float* __restrict__ up,
    ushort_t* __restrict__ downb, ushort_t* __restrict__ upb, int doCvt,
    const float* __restrict__ sk0, const float* __restrict__ sk1,
    float* __restrict__ k0n, float* __restrict__ k1n)
{
    __shared__ float smem[2 * 32 * 68];   // 17408 B
    const int bid = blockIdx.x;
    const int tid = threadIdx.x;

    if (bid < 1024) {
        // ---------------- qproj split-K=2 (round-2 body) ----------------
        float* As = smem;              // [32][68]  ([k][m])
        float* Bs = smem + 32 * 68;    // [32][68]  ([k][n])
        const int par = bid >> 9;            // 0..1  K-half
        const int rem = bid & 511;
        const int m0 = (rem >> 5) * 64;
        const int n0 = (rem & 31) * 64;
        float* qp = par ? qp1 : qp0;

        const int aM  = tid >> 3;            // 0..31
        const int aK4 = (tid & 7) * 4;       // 0..28
        const int bK  = tid >> 4;            // 0..15
        const int bN4 = (tid & 15) * 4;      // 0..60
        const int ty  = tid >> 4;            // 0..15 -> m = ty*4
        const int tx  = tid & 15;            // 0..15 -> n = tx*4

        float acc[4][4] = {};
        const int kbeg = par * 512;
        for (int kk = kbeg; kk < kbeg + 512; kk += 32) {
            __syncthreads();
#pragma unroll
            for (int p = 0; p < 2; p++) {
                int m = aM + 32 * p;
                float4 v = *(const float4*)(A + (size_t)(m0 + m) * DDIM + kk + aK4);
                As[(aK4 + 0) * 68 + m] = v.x; As[(aK4 + 1) * 68 + m] = v.y;
                As[(aK4 + 2) * 68 + m] = v.z; As[(aK4 + 3) * 68 + m] = v.w;
            }
#pragma unroll
            for (int p = 0; p < 2; p++) {
                int k = bK + 16 * p;
                float4 v = *(const float4*)(W + (size_t)(kk + k) * HQD + n0 + bN4);
                *(float4*)&Bs[k * 68 + bN4] = v;
            }
            __syncthreads();
#pragma unroll
            for (int k = 0; k < 32; k++) {
                float a[4], b[4];
                *(float4*)(a) = *(const float4*)&As[k * 68 + ty * 4];
                *(float4*)(b) = *(const float4*)&Bs[k * 68 + tx * 4];
#pragma unroll
                for (int i = 0; i < 4; i++)
#pragma unroll
                    for (int j = 0; j < 4; j++)
                        acc[i][j] = fmaf(a[i], b[j], acc[i][j]);
            }
        }
#pragma unroll
        for (int i = 0; i < 4; i++) {
            int m = m0 + ty * 4 + i;
            float4 r;
            r.x = acc[i][0]; r.y = acc[i][1]; r.z = acc[i][2]; r.w = acc[i][3];
            *(float4*)(qp + (size_t)m * HQD + n0 + tx * 4) = r;
        }
    } else if (bid < 3072) {
        // ---------------- fp32 -> bf16 table conversion ----------------
        if (!doCvt) return;
        const int cb = bid - 1024;                 // 0..2047
        const float* src = (cb < 1024) ? down : up;
        ushort_t* dst = (cb < 1024) ? downb : upb;
        const size_t base4 = (size_t)(cb & 1023) * 4096;  // float4 units
        const float4* s4 = (const float4*)src;
        ushort4* d4 = (ushort4*)dst;
#pragma unroll 4
        for (int it = 0; it < 16; it++) {
            size_t i = base4 + (size_t)it * 256 + tid;
            float4 v = s4[i];
            ushort4 o;
            o.x = f2bf(v.x); o.y = f2bf(v.y); o.z = f2bf(v.z); o.w = f2bf(v.w);
            d4[i] = o;
        }
    } else {
        // ---------------- key L2-normalize (2 rows per block) ----------------
        const int b2 = bid - 3072;                 // 0..127
        const int sub = tid >> 7;                  // 0..1
        const int col = tid & 127;
        const int gr = b2 * 2 + sub;               // 0..255
        const float* src = (gr < 128) ? sk0 : sk1;
        float* dst = (gr < 128) ? k0n : k1n;
        const int row = gr & 127;
        float v = src[row * 128 + col];
        float sq = v * v;
        for (int off = 32; off; off >>= 1) sq += __shfl_down(sq, off);
        if ((tid & 63) == 0) smem[tid >> 6] = sq;   // 4 wave leaders
        __syncthreads();
        if ((tid & 127) == 0) {
            float n = sqrtf(smem[tid >> 6] + smem[(tid >> 6) + 1]);
            smem[8 + sub] = 1.0f / fmaxf(n, 1e-12f);
        }
        __syncthreads();
        dst[row * 128 + col] = v * smem[8 + sub];
    }
}

// ---------------------------------------------------------------------------
// K2a: split-K reduce + bias + partial column sums/sumsq; writes q [8192][256]
// ---------------------------------------------------------------------------
__global__ __launch_bounds__(256) void k_bnstat1(const float* __restrict__ qp0,
                                                 const float* __restrict__ qp1,
                                                 const float* __restrict__ bq,
                                                 float* __restrict__ q,
                                                 float* __restrict__ psum,
                                                 float* __restrict__ psq)
{
    const int b = blockIdx.x;   // 0..63
    const int j = threadIdx.x;  // 0..255
    float s = 0.f, sq = 0.f;
    for (int rr = 0; rr < 128; rr++) {
        const int r = b * 128 + rr;
        const size_t g = (size_t)r * 256 + j;
        float v = qp0[g] + qp1[g] + bq[(r & 7) * 256 + j];
        q[g] = v;
        s += v; sq += v * v;
    }
    psum[b * 256 + j] = s;
    psq[b * 256 + j]  = sq;
}

// K2b: finish stats -> mean[j], scale[j] = gamma/sqrt(var+eps)
__global__ __launch_bounds__(256) void k_bnstat2(const float* __restrict__ psum,
                                                 const float* __restrict__ psq,
                                                 const float* __restrict__ gamma,
                                                 float* __restrict__ meanOut,
                                                 float* __restrict__ scaleOut)
{
    const int j = threadIdx.x;
    float s = 0.f, sq = 0.f;
    for (int b = 0; b < 64; b++) {
        s += psum[b * 256 + j];
        sq += psq[b * 256 + j];
    }
    float mean = s * (1.0f / 8192.0f);
    float var = sq * (1.0f / 8192.0f) - mean * mean;
    meanOut[j] = mean;
    scaleOut[j] = gamma[j] / sqrtf(var + 1e-5f);
}

// ---------------------------------------------------------------------------
// K4a: in-place BN transform + per-half L2 normalize of q rows [8192][256]
// ---------------------------------------------------------------------------
__global__ __launch_bounds__(256) void k_bnnorm(float* __restrict__ q,
                                                const float* __restrict__ mean,
                                                const float* __restrict__ scale,
                                                const float* __restrict__ beta)
{
    const int r = blockIdx.x * 4 + (threadIdx.x >> 6);
    const int lane = threadIdx.x & 63;
    const int j = lane * 4;
    float4 v = *(const float4*)(q + (size_t)r * 256 + j);
    float4 m = *(const float4*)(mean + j);
    float4 sc = *(const float4*)(scale + j);
    float4 be = *(const float4*)(beta + j);
    float x0 = (v.x - m.x) * sc.x + be.x;
    float x1 = (v.y - m.y) * sc.y + be.y;
    float x2 = (v.z - m.z) * sc.z + be.z;
    float x3 = (v.w - m.w) * sc.w + be.w;
    float sq = x0 * x0 + x1 * x1 + x2 * x2 + x3 * x3;
    for (int off = 16; off; off >>= 1) sq += __shfl_xor(sq, off);
    float inv = 1.0f / fmaxf(sqrtf(sq), 1e-12f);
    x0 *= inv; x1 *= inv; x2 *= inv; x3 *= inv;
    float4 o; o.x = x0; o.y = x1; o.z = x2; o.w = x3;
    *(float4*)(q + (size_t)r * 256 + j) = o;
}

// ---------------------------------------------------------------------------
// K4b: scores s_half[8192][128] = qn_half [8192][128] @ keys_half^T
// (round-2 verified body: even pads 132/68, aligned b128)
// ---------------------------------------------------------------------------
__global__ __launch_bounds__(256) void k_scores(const float* __restrict__ q,
                                                const float* __restrict__ kn0,
                                                const float* __restrict__ kn1,
                                                float* __restrict__ sOut0,
                                                float* __restrict__ sOut1)
{
    __shared__ float Ks[64 * 132];  // [d][n]
    __shared__ float Qs[64 * 68];   // [d][r]
    const int half = blockIdx.y;
    const int row0 = blockIdx.x * 64;
    const float* kn = half ? kn1 : kn0;
    float* sOut = half ? sOut1 : sOut0;
    const int tid = threadIdx.x;
    const int ty = tid >> 5;   // 0..7  -> r = ty*8
    const int tx = tid & 31;   // 0..31 -> n = tx*4
    float acc[8][4] = {};

    for (int c = 0; c < 2; c++) {
        __syncthreads();
        {
            int d4 = (tid & 15) * 4;
            int n = tid >> 4;  // 0..15
#pragma unroll
            for (int p = 0; p < 8; p++) {
                int nn = n + p * 16;
                float4 v = *(const float4*)(kn + nn * 128 + c * 64 + d4);
                Ks[(d4 + 0) * 132 + nn] = v.x; Ks[(d4 + 1) * 132 + nn] = v.y;
                Ks[(d4 + 2) * 132 + nn] = v.z; Ks[(d4 + 3) * 132 + nn] = v.w;
            }
            int r = tid >> 4;
#pragma unroll
            for (int p = 0; p < 4; p++) {
                int rr = r + p * 16;
                float4 v = *(const float4*)(q + (size_t)(row0 + rr) * 256 + half * 128 + c * 64 + d4);
                Qs[(d4 + 0) * 68 + rr] = v.x; Qs[(d4 + 1) * 68 + rr] = v.y;
                Qs[(d4 + 2) * 68 + rr] = v.z; Qs[(d4 + 3) * 68 + rr] = v.w;
            }
        }
        __syncthreads();
#pragma unroll
        for (int d = 0; d < 64; d++) {
            float a[8], b[4];
            *(float4*)(a)     = *(const float4*)&Qs[d * 68 + ty * 8];
            *(float4*)(a + 4) = *(const float4*)&Qs[d * 68 + ty * 8 + 4];
            *(float4*)(b)     = *(const float4*)&Ks[d * 132 + tx * 4];
#pragma unroll
            for (int i = 0; i < 8; i++)
#pragma unroll
                for (int j = 0; j < 4; j++)
                    acc[i][j] = fmaf(a[i], b[j], acc[i][j]);
        }
    }
#pragma unroll
    for (int i = 0; i < 8; i++) {
        float4 r;
        r.x = acc[i][0]; r.y = acc[i][1]; r.z = acc[i][2]; r.w = acc[i][3];
        *(float4*)(sOut + (size_t)(row0 + ty * 8 + i) * 128 + tx * 4) = r;
    }
}

// ---------------------------------------------------------------------------
// K4c: per (token,head) row: exact top-16 + softmax via iterative extraction.
// ---------------------------------------------------------------------------
__device__ __forceinline__ u64 mkkey(float v, u32 idx) {
    u32 ub = __float_as_uint(v);
    ub = (ub & 0x80000000u) ? ~ub : (ub | 0x80000000u);
    return ((u64)ub << 32) | (u64)(0xFFFFFFFFu - idx);
}
__device__ __forceinline__ float keyval(u64 k) {
    u32 ub = (u32)(k >> 32);
    u32 fb = (ub & 0x80000000u) ? (ub ^ 0x80000000u) : ~ub;
    return __uint_as_float(fb);
}
__device__ __forceinline__ u32 keyidx(u64 k) {
    return 0xFFFFFFFFu - (u32)(k & 0xFFFFFFFFu);
}

__global__ __launch_bounds__(256) void k_topk(const float* __restrict__ s0,
                                              const float* __restrict__ s1,
                                              int* __restrict__ tIdx,
                                              float* __restrict__ tW)
{
    __shared__ float shv[4][2][16];
    __shared__ int   shi[4][2][16];
    const int w = threadIdx.x >> 6;
    const int lane = threadIdx.x & 63;
    const int row = blockIdx.x * 4 + w;

#pragma unroll
    for (int h = 0; h < 2; h++) {
        const float* s = h ? s1 : s0;
        float v0 = s[(size_t)row * 128 + lane];
        float v1 = s[(size_t)row * 128 + 64 + lane];
        u64 k0 = mkkey(v0, (u32)lane);
        u64 k1 = mkkey(v1, (u32)(lane + 64));
        for (int r = 0; r < 16; r++) {
            u64 m = (k0 > k1) ? k0 : k1;
#pragma unroll
            for (int off = 1; off < 64; off <<= 1) {
                u64 o = __shfl_xor(m, off);
                if (o > m) m = o;
            }
            if (k0 == m) k0 = 0;
            if (k1 == m) k1 = 0;
            if (lane == 0) { shv[w][h][r] = keyval(m); shi[w][h][r] = (int)keyidx(m); }
        }
    }

    u64 ck[4];
#pragma unroll
    for (int qq = 0; qq < 4; qq++) {
        int id = lane + 64 * qq;
        int a = id >> 4, b = id & 15;
        float v = shv[w][0][a] + shv[w][1][b];
        u32 idx = (u32)(shi[w][0][a] * 128 + shi[w][1][b]);
        ck[qq] = mkkey(v, idx);
    }
    float winv = 0.f; u32 wini = 0;
    for (int r = 0; r < 16; r++) {
        u64 m = ck[0];
#pragma unroll
        for (int qq = 1; qq < 4; qq++) if (ck[qq] > m) m = ck[qq];
#pragma unroll
        for (int off = 1; off < 64; off <<= 1) {
            u64 o = __shfl_xor(m, off);
            if (o > m) m = o;
        }
#pragma unroll
        for (int qq = 0; qq < 4; qq++) if (ck[qq] == m) ck[qq] = 0;
        if (lane == r) { winv = keyval(m); wini = keyidx(m); }
    }
    float vmax = __shfl(winv, 0);
    if (lane < 16) {
        float e = expf(winv - vmax);
        float ssum = e;
#pragma unroll
        for (int off = 1; off < 16; off <<= 1) ssum += __shfl_xor(ssum, off, 16);
        tW[(size_t)row * 16 + lane] = e / ssum;
        tIdx[(size_t)row * 16 + lane] = (int)wini;
    }
}

// ---------------------------------------------------------------------------
// K5a (bf16): coef[t][p] = w[p] * gelu(down[e_p] . hidden[t])
// hidden kept in registers (16 floats/lane); 4-expert preload groups.
// ---------------------------------------------------------------------------
__global__ __launch_bounds__(1024) void k_coef_bf(const float* __restrict__ hidden,
                                                  const ushort_t* __restrict__ downb,
                                                  const int* __restrict__ tIdx,
                                                  const float* __restrict__ tW,
                                                  float* __restrict__ coef)
{
    const int t = blockIdx.x;
    const int wave = threadIdx.x >> 6, lane = threadIdx.x & 63;
    const float* hp = hidden + (size_t)t * 1024;
    float h[16];
    *(float4*)(h + 0)  = *(const float4*)(hp + lane * 8);
    *(float4*)(h + 4)  = *(const float4*)(hp + lane * 8 + 4);
    *(float4*)(h + 8)  = *(const float4*)(hp + 512 + lane * 8);
    *(float4*)(h + 12) = *(const float4*)(hp + 512 + lane * 8 + 4);

#pragma unroll
    for (int g = 0; g < 2; g++) {
        const int pg = wave * 8 + g * 4;
        float s[4];
        uint4 a[4], b[4];
#pragma unroll
        for (int i = 0; i < 4; i++) {
            const int e = tIdx[(size_t)t * 128 + pg + i];
            const uint4* rp = (const uint4*)(downb + (size_t)e * 1024);
            a[i] = rp[lane];
            b[i] = rp[lane + 64];
        }
#pragma unroll
        for (int i = 0; i < 4; i++) {
            float acc = 0.f;
            const u32* aw = (const u32*)&a[i];
            const u32* bw = (const u32*)&b[i];
#pragma unroll
            for (int c = 0; c < 4; c++) {
                acc = fmaf(bf_lo(aw[c]), h[2 * c], acc);
                acc = fmaf(bf_hi(aw[c]), h[2 * c + 1], acc);
                acc = fmaf(bf_lo(bw[c]), h[8 + 2 * c], acc);
                acc = fmaf(bf_hi(bw[c]), h[8 + 2 * c + 1], acc);
            }
            s[i] = acc;
        }
#pragma unroll
        for (int i = 0; i < 4; i++)
#pragma unroll
            for (int off = 1; off < 64; off <<= 1) s[i] += __shfl_xor(s[i], off);
        if (lane < 4) {
            float x = (lane == 0) ? s[0] : (lane == 1) ? s[1] : (lane == 2) ? s[2] : s[3];
            float wv = tW[(size_t)t * 128 + pg + lane];
            float gl = 0.5f * x * (1.0f + erff(x * 0.70710678118654752f));
            coef[(size_t)t * 128 + pg + lane] = wv * gl;
        }
    }
}

// K5a fallback (fp32 tables)
__global__ __launch_bounds__(1024) void k_coef_f32(const float* __restrict__ hidden,
                                                   const float* __restrict__ down,
                                                   const int* __restrict__ tIdx,
                                                   const float* __restrict__ tW,
                                                   float* __restrict__ coef)
{
    __shared__ __align__(16) float hs[1024];
    __shared__ int   eidx[128];
    __shared__ float wv[128];
    const int t = blockIdx.x;
    const int tid = threadIdx.x;
    hs[tid] = hidden[(size_t)t * 1024 + tid];
    if (tid < 128) {
        eidx[tid] = tIdx[(size_t)t * 128 + tid];
        wv[tid]   = tW[(size_t)t * 128 + tid];
    }
    __syncthreads();
    const int wave = tid >> 6, lane = tid & 63;
#pragma unroll 2
    for (int i = 0; i < 8; i++) {
        const int p = wave * 8 + i;
        const float4* dp = (const float4*)(down + (size_t)eidx[p] * 1024);
        float sum = 0.f;
#pragma unroll
        for (int c = 0; c < 4; c++) {
            float4 dv = dp[lane + 64 * c];
            float4 hv = *(const float4*)(hs + (lane + 64 * c) * 4);
            sum += dv.x * hv.x + dv.y * hv.y + dv.z * hv.z + dv.w * hv.w;
        }
        for (int off = 32; off; off >>= 1) sum += __shfl_down(sum, off);
        if (lane == 0) {
            float x = sum;
            float g = 0.5f * x * (1.0f + erff(x * 0.70710678118654752f));
            coef[(size_t)t * 128 + p] = wv[p] * g;
        }
    }
}

// ---------------------------------------------------------------------------
// K5b (bf16): out[t][j] = sum_p coef[t][p] * up[e_p][j]
// 256 thr: two halves of 128 threads each cover 64 experts; uint4 gathers
// (16B/lane); halves combined through LDS.
// ---------------------------------------------------------------------------
__global__ __launch_bounds__(256) void k_accum_bf(const ushort_t* __restrict__ upb,
                                                  const int* __restrict__ tIdx,
                                                  const float* __restrict__ coef,
                                                  float* __restrict__ out)
{
    __shared__ float cf[128];
    __shared__ int   ei[128];
    __shared__ float part[1024];
    const int t = blockIdx.x;
    const int tid = threadIdx.x;
    if (tid < 128) {
        cf[tid] = coef[(size_t)t * 128 + tid];
        ei[tid] = tIdx[(size_t)t * 128 + tid];
    }
    __syncthreads();
    const int half = tid >> 7;        // 0..1 -> experts [half*64, half*64+64)
    const int j8 = (tid & 127) * 8;   // 8 outputs per thread
    float acc[8] = {};
    const int p0 = half * 64;
#pragma unroll 8
    for (int p = p0; p < p0 + 64; p++) {
        const float c = cf[p];
        uint4 v = *(const uint4*)(upb + (size_t)ei[p] * 1024 + j8);
        acc[0] = fmaf(c, bf_lo(v.x), acc[0]);
        acc[1] = fmaf(c, bf_hi(v.x), acc[1]);
        acc[2] = fmaf(c, bf_lo(v.y), acc[2]);
        acc[3] = fmaf(c, bf_hi(v.y), acc[3]);
        acc[4] = fmaf(c, bf_lo(v.z), acc[4]);
        acc[5] = fmaf(c, bf_hi(v.z), acc[5]);
        acc[6] = fmaf(c, bf_lo(v.w), acc[6]);
        acc[7] = fmaf(c, bf_hi(v.w), acc[7]);
    }
    if (half == 0) {
        *(float4*)&part[j8]     = *(float4*)(acc);
        *(float4*)&part[j8 + 4] = *(float4*)(acc + 4);
    }
    __syncthreads();
    if (half == 1) {
        float4 p0v = *(float4*)&part[j8];
        float4 p1v = *(float4*)&part[j8 + 4];
        float4 r0, r1;
        r0.x = acc[0] + p0v.x; r0.y = acc[1] + p0v.y;
        r0.z = acc[2] + p0v.z; r0.w = acc[3] + p0v.w;
        r1.x = acc[4] + p1v.x; r1.y = acc[5] + p1v.y;
        r1.z = acc[6] + p1v.z; r1.w = acc[7] + p1v.w;
        *(float4*)(out + (size_t)t * 1024 + j8)     = r0;
        *(float4*)(out + (size_t)t * 1024 + j8 + 4) = r1;
    }
}

// K5b fallback (fp32 tables)
__global__ __launch_bounds__(256) void k_accum_f32(const float* __restrict__ up,
                                                   const int* __restrict__ tIdx,
                                                   const float* __restrict__ coef,
                                                   float* __restrict__ out)
{
    __shared__ float cf[128];
    __shared__ int   ei[128];
    const int t = blockIdx.x >> 2;
    const int c = blockIdx.x & 3;
    const int tid = threadIdx.x;
    if (tid < 128) {
        cf[tid] = coef[(size_t)t * 128 + tid];
        ei[tid] = tIdx[(size_t)t * 128 + tid];
    }
    __syncthreads();
    const int j = c * 256 + tid;
    float acc = 0.f;
#pragma unroll 8
    for (int p = 0; p < 128; p++)
        acc = fmaf(cf[p], up[(size_t)ei[p] * 1024 + j], acc);
    out[(size_t)t * 1024 + j] = acc;
}

// ---------------------------------------------------------------------------
extern "C" void kernel_launch(void* const* d_in, const int* in_sizes, int n_in,
                              void* d_out, int out_size, void* d_ws, size_t ws_size,
                              hipStream_t stream)
{
    const float* hidden = (const float*)d_in[0];
    const float* Wq     = (const float*)d_in[1];
    const float* bq     = (const float*)d_in[2];
    const float* gamma  = (const float*)d_in[3];
    const float* beta   = (const float*)d_in[4];
    const float* sk0    = (const float*)d_in[5];
    const float* sk1    = (const float*)d_in[6];
    const float* down   = (const float*)d_in[7];
    const float* up     = (const float*)d_in[8];
    float* out = (float*)d_out;

    float* ws = (float*)d_ws;
    size_t o = 0;
    float* qp0   = ws + o; o += (size_t)TOKENS * HQD;      // 2M floats
    float* qp1   = ws + o; o += (size_t)TOKENS * HQD;      // 2M
    float* q     = ws + o; o += (size_t)TOKENS * HQD;      // 2M
    float* ps    = ws + o; o += 64 * 256;
    float* pq    = ws + o; o += 64 * 256;
    float* meanb = ws + o; o += 256;
    float* scaleb= ws + o; o += 256;
    float* k0n   = ws + o; o += NKEY * 128;
    float* k1n   = ws + o; o += NKEY * 128;
    float* s0    = ws + o; o += (size_t)NROWS * 128;
    float* s1    = ws + o; o += (size_t)NROWS * 128;
    float* tW    = ws + o; o += (size_t)NROWS * TOPK;
    int*   tIdx  = (int*)(ws + o); o += (size_t)NROWS * TOPK;
    float* coef  = ws + o; o += (size_t)TOKENS * 128;
    // bf16 tables: 16.78M elems each -> 8.39M float slots each
    ushort_t* downb = (ushort_t*)(ws + o); o += (size_t)16384 * 1024 / 2;
    ushort_t* upb   = (ushort_t*)(ws + o); o += (size_t)16384 * 1024 / 2;
    const int useBF = (ws_size >= o * sizeof(float)) ? 1 : 0;

    k_fused1 <<<3200, 256, 0, stream>>>(hidden, Wq, qp0, qp1,
                                        down, up, downb, upb, useBF,
                                        sk0, sk1, k0n, k1n);
    k_bnstat1<<<64, 256, 0, stream>>>(qp0, qp1, bq, q, ps, pq);
    k_bnstat2<<<1, 256, 0, stream>>>(ps, pq, gamma, meanb, scaleb);
    k_bnnorm <<<2048, 256, 0, stream>>>(q, meanb, scaleb, beta);
    k_scores <<<dim3(128, 2), 256, 0, stream>>>(q, k0n, k1n, s0, s1);
    k_topk   <<<2048, 256, 0, stream>>>(s0, s1, tIdx, tW);
    if (useBF) {
        k_coef_bf <<<TOKENS, 1024, 0, stream>>>(hidden, downb, tIdx, tW, coef);
        k_accum_bf<<<TOKENS, 256, 0, stream>>>(upb, tIdx, coef, out);
    } else {
        k_coef_f32 <<<TOKENS, 1024, 0, stream>>>(hidden, down, tIdx, tW, coef);
        k_accum_f32<<<4096, 256, 0, stream>>>(up, tIdx, coef, out);
    }
}